// Round 1
// baseline (239.482 us; speedup 1.0000x reference)
//
#include <hip/hip_runtime.h>
#include <stdint.h>
#include <stddef.h>

typedef __bf16 bf16;
typedef __bf16 bf16x2 __attribute__((ext_vector_type(2)));
typedef __bf16 bf16x4 __attribute__((ext_vector_type(4)));
typedef __bf16 bf16x8 __attribute__((ext_vector_type(8)));
typedef float f32x2 __attribute__((ext_vector_type(2)));
typedef float f32x4 __attribute__((ext_vector_type(4)));

constexpr int Bb = 2, Nn = 2048, HID = 1024, Hh = 16, DH = 64;
constexpr int MTOK = Bb * Nn;   // 4096
constexpr int E3 = 3 * Hh * DH; // 3072

// ---------------- cast f32 -> bf16, vectorized ----------------
__global__ void cast_kernel(const float* __restrict__ in, bf16* __restrict__ out, int n4) {
  int i = blockIdx.x * blockDim.x + threadIdx.x;
  if (i >= n4) return;
  f32x4 v = reinterpret_cast<const f32x4*>(in)[i];
  bf16x4 o;
#pragma unroll
  for (int j = 0; j < 4; ++j) o[j] = (bf16)v[j];
  reinterpret_cast<bf16x4*>(out)[i] = o;
}

// ---------------- BT GEMM: C[M,N] = A[M,K] * Bt[N,K]^T ----------------
// m97 structure: 128x128 tile, BK=32, 4 waves (2x2), global_load_lds width 16.
template <bool OUT_BF16>
__global__ __launch_bounds__(256) void gemm_bt(const bf16* __restrict__ A,
                                               const bf16* __restrict__ Bt,
                                               void* __restrict__ Cp,
                                               int M, int N, int K) {
  __shared__ __align__(16) bf16 As[128 * 32];
  __shared__ __align__(16) bf16 Bs[128 * 32];
  const int tid = threadIdx.x;
  const int lane = tid & 63;
  const int wave = tid >> 6;
  const int wr = wave >> 1, wc = wave & 1;
  const int bm = blockIdx.x, bn = blockIdx.y;
  const int frow = lane & 15;
  const int fk = (lane >> 4) * 8;
  const int c0 = wave * 128 + lane;

  f32x4 acc[4][4] = {};

  for (int k0 = 0; k0 < K; k0 += 32) {
#pragma unroll
    for (int i = 0; i < 2; ++i) {
      int c = c0 + i * 64;               // chunk 0..511, 16B each
      int row = c >> 2;
      int col = (c & 3) * 8;
      const bf16* ga = A + (size_t)(bm * 128 + row) * K + k0 + col;
      const bf16* gb = Bt + (size_t)(bn * 128 + row) * K + k0 + col;
      __builtin_amdgcn_global_load_lds((const __attribute__((address_space(1))) void*)ga,
                                       (__attribute__((address_space(3))) void*)(As + c * 8),
                                       16, 0, 0);
      __builtin_amdgcn_global_load_lds((const __attribute__((address_space(1))) void*)gb,
                                       (__attribute__((address_space(3))) void*)(Bs + c * 8),
                                       16, 0, 0);
    }
    __syncthreads();
    bf16x8 af[4], bfr[4];
#pragma unroll
    for (int m = 0; m < 4; ++m)
      af[m] = *reinterpret_cast<const bf16x8*>(As + (wr * 64 + m * 16 + frow) * 32 + fk);
#pragma unroll
    for (int n = 0; n < 4; ++n)
      bfr[n] = *reinterpret_cast<const bf16x8*>(Bs + (wc * 64 + n * 16 + frow) * 32 + fk);
#pragma unroll
    for (int m = 0; m < 4; ++m)
#pragma unroll
      for (int n = 0; n < 4; ++n)
        acc[m][n] = __builtin_amdgcn_mfma_f32_16x16x32_bf16(af[m], bfr[n], acc[m][n], 0, 0, 0);
    __syncthreads();
  }

  const int r0 = bm * 128 + wr * 64;
  const int cc0 = bn * 128 + wc * 64;
#pragma unroll
  for (int m = 0; m < 4; ++m)
#pragma unroll
    for (int n = 0; n < 4; ++n)
#pragma unroll
      for (int r = 0; r < 4; ++r) {
        int row = r0 + m * 16 + (lane >> 4) * 4 + r;
        int col = cc0 + n * 16 + frow;
        if (OUT_BF16)
          ((bf16*)Cp)[(size_t)row * N + col] = (bf16)acc[m][n][r];
        else
          ((float*)Cp)[(size_t)row * N + col] = acc[m][n][r];
      }
}

// ---------------- RoPE + repack: qkv[B,N,3,H,DH] -> q,k [B,H,N,DH], vT [B,H,DH,N] ----------------
__global__ __launch_bounds__(256) void rope_pack(const bf16* __restrict__ qkvb,
                                                 const float* __restrict__ rope,
                                                 bf16* __restrict__ qb,
                                                 bf16* __restrict__ kb,
                                                 bf16* __restrict__ vT) {
  __shared__ bf16 vt[128][66];  // padded: stride 132B -> conflict-free transpose
  const int bh = blockIdx.y;
  const int b = bh >> 4;
  const int h = bh & 15;
  const int n0 = blockIdx.x * 128;
  const int t = threadIdx.x;

  for (int it = 0; it < 16; ++it) {
    int p = it * 256 + t;   // 0..4095 : (row 0..127) x (pair 0..31)
    int nl = p >> 5, i = p & 31;
    int n = n0 + nl;
    size_t rowbase = (size_t)(b * Nn + n);
    const bf16* src = qkvb + rowbase * E3 + h * DH + 2 * i;
    f32x2 cs = *reinterpret_cast<const f32x2*>(rope + rowbase * DH + 2 * i);
    float c = cs[0], sn = cs[1];
    bf16x2 qv = *reinterpret_cast<const bf16x2*>(src);
    bf16x2 kv = *reinterpret_cast<const bf16x2*>(src + HID);
    bf16x2 vv = *reinterpret_cast<const bf16x2*>(src + 2 * HID);
    float q0 = (float)qv[0], q1 = (float)qv[1];
    float k0 = (float)kv[0], k1 = (float)kv[1];
    bf16x2 qo, ko;
    qo[0] = (bf16)(q0 * c - q1 * sn);
    qo[1] = (bf16)(q1 * c + q0 * sn);
    ko[0] = (bf16)(k0 * c - k1 * sn);
    ko[1] = (bf16)(k1 * c + k0 * sn);
    size_t obase = ((size_t)bh * Nn + n) * DH + 2 * i;
    *reinterpret_cast<bf16x2*>(qb + obase) = qo;
    *reinterpret_cast<bf16x2*>(kb + obase) = ko;
    vt[nl][2 * i] = vv[0];
    vt[nl][2 * i + 1] = vv[1];
  }
  __syncthreads();
  for (int it = 0; it < 32; ++it) {
    int u = it * 256 + t;   // 0..8191 : (d 0..63) x (nl 0..127), nl fastest -> coalesced store
    int d = u >> 7, nl = u & 127;
    vT[((size_t)bh * DH + d) * Nn + n0 + nl] = vt[nl][d];
  }
}

// ---------------- flash attention: per (b,h,qtile=128), 4 waves x 32 q-rows ----------------
__global__ __launch_bounds__(256) void attn_kernel(const bf16* __restrict__ qb,
                                                   const bf16* __restrict__ kb,
                                                   const bf16* __restrict__ vT,
                                                   bf16* __restrict__ outb) {
  __shared__ __align__(16) bf16 Ps[4][32 * 128];  // per-wave private P tile
  const int lane = threadIdx.x & 63;
  const int wave = threadIdx.x >> 6;
  const int qt = blockIdx.x;
  const int bh = blockIdx.y;
  const int b = bh >> 4, h = bh & 15;
  const int frow = lane & 15;
  const int fk = (lane >> 4) * 8;
  const int q0 = qt * 128 + wave * 32;
  const bf16* qptr = qb + (size_t)bh * Nn * DH;
  const bf16* kptr = kb + (size_t)bh * Nn * DH;
  const bf16* vptr = vT + (size_t)bh * DH * Nn;
  char* myPc = (char*)&Ps[wave][0];

  // Q fragments hoisted to registers (A-operand: row=lane&15, k=(lane>>4)*8)
  bf16x8 aq[2][2];
#pragma unroll
  for (int m = 0; m < 2; ++m)
#pragma unroll
    for (int kk = 0; kk < 2; ++kk)
      aq[m][kk] = *reinterpret_cast<const bf16x8*>(
          qptr + (size_t)(q0 + m * 16 + frow) * DH + kk * 32 + fk);

  float mrow[2][4], lrow[2][4];
  f32x4 oacc[2][4] = {};
#pragma unroll
  for (int m = 0; m < 2; ++m)
#pragma unroll
    for (int r = 0; r < 4; ++r) { mrow[m][r] = -1e30f; lrow[m][r] = 0.f; }

  for (int t = 0; t < 16; ++t) {
    const int key0 = t * 128;
    // S = Q K^T  (K fragments straight from global; K/V are L2-resident)
    f32x4 s[2][8] = {};
#pragma unroll
    for (int kk = 0; kk < 2; ++kk) {
      bf16x8 bk[8];
#pragma unroll
      for (int n = 0; n < 8; ++n)
        bk[n] = *reinterpret_cast<const bf16x8*>(
            kptr + (size_t)(key0 + n * 16 + frow) * DH + kk * 32 + fk);
#pragma unroll
      for (int m = 0; m < 2; ++m)
#pragma unroll
        for (int n = 0; n < 8; ++n)
          s[m][n] = __builtin_amdgcn_mfma_f32_16x16x32_bf16(aq[m][kk], bk[n], s[m][n], 0, 0, 0);
    }
#pragma unroll
    for (int m = 0; m < 2; ++m)
#pragma unroll
      for (int n = 0; n < 8; ++n)
        s[m][n] = s[m][n] * 0.125f;  // DH^-0.5

    // online softmax: rows live in 16-lane groups -> shfl_xor reduce
#pragma unroll
    for (int m = 0; m < 2; ++m)
#pragma unroll
      for (int r = 0; r < 4; ++r) {
        float tm = s[m][0][r];
#pragma unroll
        for (int n = 1; n < 8; ++n) tm = fmaxf(tm, s[m][n][r]);
        tm = fmaxf(tm, __shfl_xor(tm, 1));
        tm = fmaxf(tm, __shfl_xor(tm, 2));
        tm = fmaxf(tm, __shfl_xor(tm, 4));
        tm = fmaxf(tm, __shfl_xor(tm, 8));
        float mn = fmaxf(mrow[m][r], tm);
        float corr = __expf(mrow[m][r] - mn);
        mrow[m][r] = mn;
        float ts = 0.f;
#pragma unroll
        for (int n = 0; n < 8; ++n) {
          float e = __expf(s[m][n][r] - mn);
          s[m][n][r] = e;
          ts += e;
        }
        ts += __shfl_xor(ts, 1);
        ts += __shfl_xor(ts, 2);
        ts += __shfl_xor(ts, 4);
        ts += __shfl_xor(ts, 8);
        lrow[m][r] = lrow[m][r] * corr + ts;
#pragma unroll
        for (int n = 0; n < 4; ++n) oacc[m][n][r] *= corr;
      }

    // write P (bf16) to per-wave LDS, XOR-swizzled (G4). Same wave reads back -> no barrier.
#pragma unroll
    for (int m = 0; m < 2; ++m)
#pragma unroll
      for (int n = 0; n < 8; ++n)
#pragma unroll
        for (int r = 0; r < 4; ++r) {
          int rl = m * 16 + (lane >> 4) * 4 + r;
          int byte = (rl * 256 + (n * 16 + frow) * 2) ^ ((rl & 7) << 4);
          *(bf16*)(myPc + byte) = (bf16)s[m][n][r];
        }

    // PV: A = P from LDS (swizzled read), B = vT rows (k-contiguous)
    bf16x8 pa[2][4];
#pragma unroll
    for (int m = 0; m < 2; ++m)
#pragma unroll
      for (int ks = 0; ks < 4; ++ks) {
        int rl = m * 16 + frow;
        int byte = (rl * 256 + (ks * 32 + fk) * 2) ^ ((rl & 7) << 4);
        pa[m][ks] = *reinterpret_cast<const bf16x8*>(myPc + byte);
      }
#pragma unroll
    for (int ks = 0; ks < 4; ++ks)
#pragma unroll
      for (int n = 0; n < 4; ++n) {
        bf16x8 vb = *reinterpret_cast<const bf16x8*>(
            vptr + (size_t)(n * 16 + frow) * Nn + key0 + ks * 32 + fk);
#pragma unroll
        for (int m = 0; m < 2; ++m)
          oacc[m][n] = __builtin_amdgcn_mfma_f32_16x16x32_bf16(pa[m][ks], vb, oacc[m][n], 0, 0, 0);
      }
  }

  // epilogue: O /= l, write bf16 into [B,N,H*DH]
#pragma unroll
  for (int m = 0; m < 2; ++m)
#pragma unroll
    for (int n = 0; n < 4; ++n)
#pragma unroll
      for (int r = 0; r < 4; ++r) {
        int row = q0 + m * 16 + (lane >> 4) * 4 + r;
        int col = h * DH + n * 16 + frow;
        float v = oacc[m][n][r] / lrow[m][r];
        outb[(size_t)(b * Nn + row) * HID + col] = (bf16)v;
      }
}

// ---------------- launch ----------------
extern "C" void kernel_launch(void* const* d_in, const int* in_sizes, int n_in,
                              void* d_out, int out_size, void* d_ws, size_t ws_size,
                              hipStream_t stream) {
  const float* x = (const float*)d_in[0];
  const float* rope = (const float*)d_in[1];
  const float* Wqkv = (const float*)d_in[2];
  const float* Wout = (const float*)d_in[3];
  float* out = (float*)d_out;

  char* w = (char*)d_ws;
  size_t off = 0;
  auto alloc = [&](size_t bytes) -> void* {
    void* p = w + off;
    off += (bytes + 255) & ~(size_t)255;
    return p;
  };
  bf16* xb    = (bf16*)alloc((size_t)MTOK * HID * 2);
  bf16* wqkvb = (bf16*)alloc((size_t)E3 * HID * 2);
  bf16* woutb = (bf16*)alloc((size_t)HID * HID * 2);
  bf16* qkvb  = (bf16*)alloc((size_t)MTOK * E3 * 2);
  bf16* qbuf  = (bf16*)alloc((size_t)Bb * Hh * Nn * DH * 2);
  bf16* kbuf  = (bf16*)alloc((size_t)Bb * Hh * Nn * DH * 2);
  bf16* vTbuf = (bf16*)alloc((size_t)Bb * Hh * Nn * DH * 2);
  bf16* attno = (bf16*)alloc((size_t)MTOK * HID * 2);

  cast_kernel<<<(MTOK * HID / 4) / 256, 256, 0, stream>>>(x, xb, MTOK * HID / 4);
  cast_kernel<<<(E3 * HID / 4) / 256, 256, 0, stream>>>(Wqkv, wqkvb, E3 * HID / 4);
  cast_kernel<<<(HID * HID / 4) / 256, 256, 0, stream>>>(Wout, woutb, HID * HID / 4);

  gemm_bt<true><<<dim3(MTOK / 128, E3 / 128), 256, 0, stream>>>(xb, wqkvb, qkvb, MTOK, E3, HID);

  rope_pack<<<dim3(Nn / 128, Bb * Hh), 256, 0, stream>>>(qkvb, rope, qbuf, kbuf, vTbuf);

  attn_kernel<<<dim3(Nn / 128, Bb * Hh), 256, 0, stream>>>(qbuf, kbuf, vTbuf, attno);

  gemm_bt<false><<<dim3(MTOK / 128, HID / 128), 256, 0, stream>>>(attno, woutb, out, MTOK, HID, HID);
}

// Round 4
// 206.731 us; speedup vs baseline: 1.1584x; 1.1584x over previous
//
#include <hip/hip_runtime.h>
#include <stdint.h>
#include <stddef.h>

typedef __bf16 bf16;
typedef __bf16 bf16x2 __attribute__((ext_vector_type(2)));
typedef __bf16 bf16x4 __attribute__((ext_vector_type(4)));
typedef __bf16 bf16x8 __attribute__((ext_vector_type(8)));
typedef float f32x2 __attribute__((ext_vector_type(2)));
typedef float f32x4 __attribute__((ext_vector_type(4)));
typedef float f32x16 __attribute__((ext_vector_type(16)));

constexpr int Bb = 2, Nn = 2048, HID = 1024, Hh = 16, DH = 64;
constexpr int MTOK = Bb * Nn;   // 4096
constexpr int E3 = 3 * Hh * DH; // 3072

// ---------------- cast f32 -> bf16, vectorized ----------------
__global__ void cast_kernel(const float* __restrict__ in, bf16* __restrict__ out, int n4) {
  int i = blockIdx.x * blockDim.x + threadIdx.x;
  if (i >= n4) return;
  f32x4 v = reinterpret_cast<const f32x4*>(in)[i];
  bf16x4 o;
#pragma unroll
  for (int j = 0; j < 4; ++j) o[j] = (bf16)v[j];
  reinterpret_cast<bf16x4*>(out)[i] = o;
}

// ---------------- BT GEMM: C[M,N] = A[M,K] * Bt[N,K]^T ----------------
template <bool OUT_BF16>
__global__ __launch_bounds__(256) void gemm_bt(const bf16* __restrict__ A,
                                               const bf16* __restrict__ Bt,
                                               void* __restrict__ Cp,
                                               int M, int N, int K) {
  __shared__ __align__(16) bf16 As[128 * 32];
  __shared__ __align__(16) bf16 Bs[128 * 32];
  const int tid = threadIdx.x;
  const int lane = tid & 63;
  const int wave = tid >> 6;
  const int wr = wave >> 1, wc = wave & 1;
  const int bm = blockIdx.x, bn = blockIdx.y;
  const int frow = lane & 15;
  const int fk = (lane >> 4) * 8;
  const int c0 = wave * 128 + lane;

  f32x4 acc[4][4] = {};

  for (int k0 = 0; k0 < K; k0 += 32) {
#pragma unroll
    for (int i = 0; i < 2; ++i) {
      int c = c0 + i * 64;               // chunk 0..511, 16B each
      int row = c >> 2;
      int col = (c & 3) * 8;
      const bf16* ga = A + (size_t)(bm * 128 + row) * K + k0 + col;
      const bf16* gb = Bt + (size_t)(bn * 128 + row) * K + k0 + col;
      __builtin_amdgcn_global_load_lds((const __attribute__((address_space(1))) void*)ga,
                                       (__attribute__((address_space(3))) void*)(As + c * 8),
                                       16, 0, 0);
      __builtin_amdgcn_global_load_lds((const __attribute__((address_space(1))) void*)gb,
                                       (__attribute__((address_space(3))) void*)(Bs + c * 8),
                                       16, 0, 0);
    }
    __syncthreads();
    bf16x8 af[4], bfr[4];
#pragma unroll
    for (int m = 0; m < 4; ++m)
      af[m] = *reinterpret_cast<const bf16x8*>(As + (wr * 64 + m * 16 + frow) * 32 + fk);
#pragma unroll
    for (int n = 0; n < 4; ++n)
      bfr[n] = *reinterpret_cast<const bf16x8*>(Bs + (wc * 64 + n * 16 + frow) * 32 + fk);
#pragma unroll
    for (int m = 0; m < 4; ++m)
#pragma unroll
      for (int n = 0; n < 4; ++n)
        acc[m][n] = __builtin_amdgcn_mfma_f32_16x16x32_bf16(af[m], bfr[n], acc[m][n], 0, 0, 0);
    __syncthreads();
  }

  const int r0 = bm * 128 + wr * 64;
  const int cc0 = bn * 128 + wc * 64;
#pragma unroll
  for (int m = 0; m < 4; ++m)
#pragma unroll
    for (int n = 0; n < 4; ++n)
#pragma unroll
      for (int r = 0; r < 4; ++r) {
        int row = r0 + m * 16 + (lane >> 4) * 4 + r;
        int col = cc0 + n * 16 + frow;
        if (OUT_BF16)
          ((bf16*)Cp)[(size_t)row * N + col] = (bf16)acc[m][n][r];
        else
          ((float*)Cp)[(size_t)row * N + col] = acc[m][n][r];
      }
}

// ---------------- RoPE + repack: qkv[B,N,3,H,DH] -> q,k [B,H,N,DH], vT [B,H,DH,N] ----------------
__global__ __launch_bounds__(256) void rope_pack(const bf16* __restrict__ qkvb,
                                                 const float* __restrict__ rope,
                                                 bf16* __restrict__ qb,
                                                 bf16* __restrict__ kb,
                                                 bf16* __restrict__ vT) {
  __shared__ bf16 vt[128][66];  // padded: conflict-free transpose
  const int bh = blockIdx.y;
  const int b = bh >> 4;
  const int h = bh & 15;
  const int n0 = blockIdx.x * 128;
  const int t = threadIdx.x;

  for (int it = 0; it < 16; ++it) {
    int p = it * 256 + t;   // (row 0..127) x (pair 0..31)
    int nl = p >> 5, i = p & 31;
    int n = n0 + nl;
    size_t rowbase = (size_t)(b * Nn + n);
    const bf16* src = qkvb + rowbase * E3 + h * DH + 2 * i;
    f32x2 cs = *reinterpret_cast<const f32x2*>(rope + rowbase * DH + 2 * i);
    float c = cs[0], sn = cs[1];
    bf16x2 qv = *reinterpret_cast<const bf16x2*>(src);
    bf16x2 kv = *reinterpret_cast<const bf16x2*>(src + HID);
    bf16x2 vv = *reinterpret_cast<const bf16x2*>(src + 2 * HID);
    float q0 = (float)qv[0], q1 = (float)qv[1];
    float k0 = (float)kv[0], k1 = (float)kv[1];
    bf16x2 qo, ko;
    qo[0] = (bf16)(q0 * c - q1 * sn);
    qo[1] = (bf16)(q1 * c + q0 * sn);
    ko[0] = (bf16)(k0 * c - k1 * sn);
    ko[1] = (bf16)(k1 * c + k0 * sn);
    size_t obase = ((size_t)bh * Nn + n) * DH + 2 * i;
    *reinterpret_cast<bf16x2*>(qb + obase) = qo;
    *reinterpret_cast<bf16x2*>(kb + obase) = ko;
    vt[nl][2 * i] = vv[0];
    vt[nl][2 * i + 1] = vv[1];
  }
  __syncthreads();
  for (int it = 0; it < 32; ++it) {
    int u = it * 256 + t;   // (d 0..63) x (nl 0..127)
    int d = u >> 7, nl = u & 127;
    vT[((size_t)bh * DH + d) * Nn + n0 + nl] = vt[nl][d];
  }
}

// ---------------- flash attention: swapped QK^T, in-register softmax, no LDS ----------------
// Per wave: 32 q-rows. S^T = K·Q^T via mfma_32x32x16 (lane = q-column, 16 k-rows in regs).
__global__ __launch_bounds__(256, 2) void attn_kernel(const bf16* __restrict__ qb,
                                                      const bf16* __restrict__ kb,
                                                      const bf16* __restrict__ vT,
                                                      bf16* __restrict__ outb) {
  const int lane = threadIdx.x & 63;
  const int wave = threadIdx.x >> 6;
  const int qt = blockIdx.x;
  const int bh = blockIdx.y;
  const int b = bh >> 4, h = bh & 15;
  const int lo = lane & 31;
  const int hi = lane >> 5;
  const int q0 = qt * 128 + wave * 32;
  const bf16* qptr = qb + (size_t)bh * Nn * DH;
  const bf16* kptr = kb + (size_t)bh * Nn * DH;
  const bf16* vptr = vT + (size_t)bh * DH * Nn;

  constexpr float SCL = 0.125f * 1.44269504088896340736f;  // dh^-0.5 * log2(e)

  // Q as B-operand: B[t=dh][c=q], c=lo, t = d*16 + hi*8 + j
  bf16x8 qf[4];
#pragma unroll
  for (int d = 0; d < 4; ++d)
    qf[d] = *reinterpret_cast<const bf16x8*>(qptr + (size_t)(q0 + lo) * DH + d * 16 + hi * 8);

  f32x16 o0 = {}, o1 = {};
  float mrun = -3e38f, lrun = 0.f;

  auto loadK = [&](int key0, bf16x8* kf) {
#pragma unroll
    for (int d = 0; d < 4; ++d)
      kf[d] = *reinterpret_cast<const bf16x8*>(kptr + (size_t)(key0 + lo) * DH + d * 16 + hi * 8);
  };
  auto loadV = [&](int key0, bf16x8* vf) {
#pragma unroll
    for (int dt = 0; dt < 2; ++dt)
#pragma unroll
      for (int kbi = 0; kbi < 2; ++kbi)
        vf[dt * 2 + kbi] = *reinterpret_cast<const bf16x8*>(
            vptr + (size_t)(dt * 32 + lo) * Nn + key0 + kbi * 16 + hi * 8);
  };

  auto cvtpk = [](float a, float b) {
    unsigned w;
    asm("v_cvt_pk_bf16_f32 %0, %1, %2" : "=v"(w) : "v"(a), "v"(b));
    return w;
  };

  auto tilestep = [&](const bf16x8* kf, const bf16x8* vf) {
    f32x16 s = {};
#pragma unroll
    for (int d = 0; d < 4; ++d)
      s = __builtin_amdgcn_mfma_f32_32x32x16_bf16(kf[d], qf[d], s, 0, 0, 0);

    // row-max over 32 k for this lane's q-column
    float tm = s[0];
#pragma unroll
    for (int r = 1; r < 16; ++r) tm = fmaxf(tm, s[r]);
    tm = fmaxf(tm, __shfl_xor(tm, 32));
    float tms = tm * SCL;

    // T13 defer-max: rescale only when max grows past threshold (wave-uniform branch)
    if (__any(tms > mrun + 8.0f)) {
      float mn = fmaxf(mrun, tms);
      float corr = __builtin_amdgcn_exp2f(mrun - mn);
      mrun = mn;
      lrun *= corr;
#pragma unroll
      for (int r = 0; r < 16; ++r) { o0[r] *= corr; o1[r] *= corr; }
    }

    float e[16];
    float ts = 0.f;
#pragma unroll
    for (int r = 0; r < 16; ++r) {
      e[r] = __builtin_amdgcn_exp2f(fmaf(s[r], SCL, -mrun));
      ts += e[r];
    }
    ts += __shfl_xor(ts, 32);
    lrun += ts;

    // P^T (f32 regs) -> bf16 B-fragments for PV, in-register (T12, shfl variant).
    // Acc reg r holds k = (r&3) + 8*(r>>2) + 4*hi.
    // B-frag for k-block kbi needs k = kbi*16 + hi*8 + j.
    //   hi=0 lane: keeps own e[kbi*8+0..3] (k=kbi*16+0..3), needs partner e[kbi*8+0..3] (k=+4..7)
    //   hi=1 lane: keeps own e[kbi*8+4..7] (k=kbi*16+12..15), needs partner e[kbi*8+4..7] (k=+8..11)
    // => each lane SENDS the half its partner needs: hi=0 sends Y (e[4..7]), hi=1 sends X (e[0..3]).
    union { unsigned w[4]; bf16x8 v8; } pb[2];
#pragma unroll
    for (int kbi = 0; kbi < 2; ++kbi) {
      unsigned X0 = cvtpk(e[kbi * 8 + 0], e[kbi * 8 + 1]);
      unsigned X1 = cvtpk(e[kbi * 8 + 2], e[kbi * 8 + 3]);
      unsigned Y0 = cvtpk(e[kbi * 8 + 4], e[kbi * 8 + 5]);
      unsigned Y1 = cvtpk(e[kbi * 8 + 6], e[kbi * 8 + 7]);
      unsigned S0 = hi ? X0 : Y0;        // what the partner needs
      unsigned S1 = hi ? X1 : Y1;
      unsigned T0 = __shfl_xor(S0, 32);  // what we need from partner
      unsigned T1 = __shfl_xor(S1, 32);
      pb[kbi].w[0] = hi ? T0 : X0;
      pb[kbi].w[1] = hi ? T1 : X1;
      pb[kbi].w[2] = hi ? Y0 : T0;
      pb[kbi].w[3] = hi ? Y1 : T1;
    }

    // PV: O^T[dh,q] += V^T[dh,k] P^T[k,q]
    o0 = __builtin_amdgcn_mfma_f32_32x32x16_bf16(vf[0], pb[0].v8, o0, 0, 0, 0);
    o0 = __builtin_amdgcn_mfma_f32_32x32x16_bf16(vf[1], pb[1].v8, o0, 0, 0, 0);
    o1 = __builtin_amdgcn_mfma_f32_32x32x16_bf16(vf[2], pb[0].v8, o1, 0, 0, 0);
    o1 = __builtin_amdgcn_mfma_f32_32x32x16_bf16(vf[3], pb[1].v8, o1, 0, 0, 0);
  };

  // double-buffered K/V fragments, prefetch one tile ahead
  bf16x8 kA[4], vA[4], kB[4], vB[4];
  loadK(0, kA);
  loadV(0, vA);
  for (int t = 0; t < 64; t += 2) {
    int n1 = (t + 1) * 32;
    loadK(n1, kB);
    loadV(n1, vB);
    tilestep(kA, vA);
    int n2 = (t + 2 < 64) ? (t + 2) * 32 : 0;  // last prefetch harmless
    loadK(n2, kA);
    loadV(n2, vA);
    tilestep(kB, vB);
  }

  // epilogue: O^T/l -> outb[B,N,H*DH]; lane owns q-row q0+lo
  float invl = 1.0f / lrun;
#pragma unroll
  for (int dt = 0; dt < 2; ++dt) {
#pragma unroll
    for (int g = 0; g < 4; ++g) {
      bf16x4 ov;
#pragma unroll
      for (int j = 0; j < 4; ++j) {
        float val = (dt ? o1[g * 4 + j] : o0[g * 4 + j]) * invl;
        ov[j] = (bf16)val;
      }
      int dh = dt * 32 + g * 8 + hi * 4;
      *reinterpret_cast<bf16x4*>(outb + (size_t)(b * Nn + q0 + lo) * HID + h * DH + dh) = ov;
    }
  }
}

// ---------------- launch ----------------
extern "C" void kernel_launch(void* const* d_in, const int* in_sizes, int n_in,
                              void* d_out, int out_size, void* d_ws, size_t ws_size,
                              hipStream_t stream) {
  const float* x = (const float*)d_in[0];
  const float* rope = (const float*)d_in[1];
  const float* Wqkv = (const float*)d_in[2];
  const float* Wout = (const float*)d_in[3];
  float* out = (float*)d_out;

  char* w = (char*)d_ws;
  size_t off = 0;
  auto alloc = [&](size_t bytes) -> void* {
    void* p = w + off;
    off += (bytes + 255) & ~(size_t)255;
    return p;
  };
  bf16* xb    = (bf16*)alloc((size_t)MTOK * HID * 2);
  bf16* wqkvb = (bf16*)alloc((size_t)E3 * HID * 2);
  bf16* woutb = (bf16*)alloc((size_t)HID * HID * 2);
  bf16* qkvb  = (bf16*)alloc((size_t)MTOK * E3 * 2);
  bf16* qbuf  = (bf16*)alloc((size_t)Bb * Hh * Nn * DH * 2);
  bf16* kbuf  = (bf16*)alloc((size_t)Bb * Hh * Nn * DH * 2);
  bf16* vTbuf = (bf16*)alloc((size_t)Bb * Hh * Nn * DH * 2);
  bf16* attno = (bf16*)alloc((size_t)MTOK * HID * 2);

  cast_kernel<<<(MTOK * HID / 4) / 256, 256, 0, stream>>>(x, xb, MTOK * HID / 4);
  cast_kernel<<<(E3 * HID / 4) / 256, 256, 0, stream>>>(Wqkv, wqkvb, E3 * HID / 4);
  cast_kernel<<<(HID * HID / 4) / 256, 256, 0, stream>>>(Wout, woutb, HID * HID / 4);

  gemm_bt<true><<<dim3(MTOK / 128, E3 / 128), 256, 0, stream>>>(xb, wqkvb, qkvb, MTOK, E3, HID);

  rope_pack<<<dim3(Nn / 128, Bb * Hh), 256, 0, stream>>>(qkvb, rope, qbuf, kbuf, vTbuf);

  attn_kernel<<<dim3(Nn / 128, Bb * Hh), 256, 0, stream>>>(qbuf, kbuf, vTbuf, attno);

  gemm_bt<false><<<dim3(MTOK / 128, HID / 128), 256, 0, stream>>>(attno, woutb, out, MTOK, HID, HID);
}

// Round 5
// 205.377 us; speedup vs baseline: 1.1661x; 1.0066x over previous
//
#include <hip/hip_runtime.h>
#include <stdint.h>
#include <stddef.h>

typedef __bf16 bf16;
typedef __bf16 bf16x2 __attribute__((ext_vector_type(2)));
typedef __bf16 bf16x4 __attribute__((ext_vector_type(4)));
typedef __bf16 bf16x8 __attribute__((ext_vector_type(8)));
typedef float f32x2 __attribute__((ext_vector_type(2)));
typedef float f32x4 __attribute__((ext_vector_type(4)));
typedef float f32x16 __attribute__((ext_vector_type(16)));

constexpr int Bb = 2, Nn = 2048, HID = 1024, Hh = 16, DH = 64;
constexpr int MTOK = Bb * Nn;   // 4096
constexpr int E3 = 3 * Hh * DH; // 3072

// ---------------- cast f32 -> bf16, vectorized ----------------
__global__ void cast_kernel(const float* __restrict__ in, bf16* __restrict__ out, int n4) {
  int i = blockIdx.x * blockDim.x + threadIdx.x;
  if (i >= n4) return;
  f32x4 v = reinterpret_cast<const f32x4*>(in)[i];
  bf16x4 o;
#pragma unroll
  for (int j = 0; j < 4; ++j) o[j] = (bf16)v[j];
  reinterpret_cast<bf16x4*>(out)[i] = o;
}

// ---------------- BT GEMM: C[M,N] = A[M,K] * Bt[N,K]^T ----------------
template <bool OUT_BF16>
__global__ __launch_bounds__(256) void gemm_bt(const bf16* __restrict__ A,
                                               const bf16* __restrict__ Bt,
                                               void* __restrict__ Cp,
                                               int M, int N, int K) {
  __shared__ __align__(16) bf16 As[128 * 32];
  __shared__ __align__(16) bf16 Bs[128 * 32];
  const int tid = threadIdx.x;
  const int lane = tid & 63;
  const int wave = tid >> 6;
  const int wr = wave >> 1, wc = wave & 1;
  const int bm = blockIdx.x, bn = blockIdx.y;
  const int frow = lane & 15;
  const int fk = (lane >> 4) * 8;
  const int c0 = wave * 128 + lane;

  f32x4 acc[4][4] = {};

  for (int k0 = 0; k0 < K; k0 += 32) {
#pragma unroll
    for (int i = 0; i < 2; ++i) {
      int c = c0 + i * 64;               // chunk 0..511, 16B each
      int row = c >> 2;
      int col = (c & 3) * 8;
      const bf16* ga = A + (size_t)(bm * 128 + row) * K + k0 + col;
      const bf16* gb = Bt + (size_t)(bn * 128 + row) * K + k0 + col;
      __builtin_amdgcn_global_load_lds((const __attribute__((address_space(1))) void*)ga,
                                       (__attribute__((address_space(3))) void*)(As + c * 8),
                                       16, 0, 0);
      __builtin_amdgcn_global_load_lds((const __attribute__((address_space(1))) void*)gb,
                                       (__attribute__((address_space(3))) void*)(Bs + c * 8),
                                       16, 0, 0);
    }
    __syncthreads();
    bf16x8 af[4], bfr[4];
#pragma unroll
    for (int m = 0; m < 4; ++m)
      af[m] = *reinterpret_cast<const bf16x8*>(As + (wr * 64 + m * 16 + frow) * 32 + fk);
#pragma unroll
    for (int n = 0; n < 4; ++n)
      bfr[n] = *reinterpret_cast<const bf16x8*>(Bs + (wc * 64 + n * 16 + frow) * 32 + fk);
#pragma unroll
    for (int m = 0; m < 4; ++m)
#pragma unroll
      for (int n = 0; n < 4; ++n)
        acc[m][n] = __builtin_amdgcn_mfma_f32_16x16x32_bf16(af[m], bfr[n], acc[m][n], 0, 0, 0);
    __syncthreads();
  }

  const int r0 = bm * 128 + wr * 64;
  const int cc0 = bn * 128 + wc * 64;
#pragma unroll
  for (int m = 0; m < 4; ++m)
#pragma unroll
    for (int n = 0; n < 4; ++n)
#pragma unroll
      for (int r = 0; r < 4; ++r) {
        int row = r0 + m * 16 + (lane >> 4) * 4 + r;
        int col = cc0 + n * 16 + frow;
        if (OUT_BF16)
          ((bf16*)Cp)[(size_t)row * N + col] = (bf16)acc[m][n][r];
        else
          ((float*)Cp)[(size_t)row * N + col] = acc[m][n][r];
      }
}

// ---------------- RoPE + repack: qkv[B,N,3,H,DH] -> q,k [B,H,N,DH], vT [B,H,DH,N] ----------------
__global__ __launch_bounds__(256) void rope_pack(const bf16* __restrict__ qkvb,
                                                 const float* __restrict__ rope,
                                                 bf16* __restrict__ qb,
                                                 bf16* __restrict__ kb,
                                                 bf16* __restrict__ vT) {
  __shared__ bf16 vt[128][66];  // padded: conflict-free transpose
  const int bh = blockIdx.y;
  const int b = bh >> 4;
  const int h = bh & 15;
  const int n0 = blockIdx.x * 128;
  const int t = threadIdx.x;

  for (int it = 0; it < 16; ++it) {
    int p = it * 256 + t;   // (row 0..127) x (pair 0..31)
    int nl = p >> 5, i = p & 31;
    int n = n0 + nl;
    size_t rowbase = (size_t)(b * Nn + n);
    const bf16* src = qkvb + rowbase * E3 + h * DH + 2 * i;
    f32x2 cs = *reinterpret_cast<const f32x2*>(rope + rowbase * DH + 2 * i);
    float c = cs[0], sn = cs[1];
    bf16x2 qv = *reinterpret_cast<const bf16x2*>(src);
    bf16x2 kv = *reinterpret_cast<const bf16x2*>(src + HID);
    bf16x2 vv = *reinterpret_cast<const bf16x2*>(src + 2 * HID);
    float q0 = (float)qv[0], q1 = (float)qv[1];
    float k0 = (float)kv[0], k1 = (float)kv[1];
    bf16x2 qo, ko;
    qo[0] = (bf16)(q0 * c - q1 * sn);
    qo[1] = (bf16)(q1 * c + q0 * sn);
    ko[0] = (bf16)(k0 * c - k1 * sn);
    ko[1] = (bf16)(k1 * c + k0 * sn);
    size_t obase = ((size_t)bh * Nn + n) * DH + 2 * i;
    *reinterpret_cast<bf16x2*>(qb + obase) = qo;
    *reinterpret_cast<bf16x2*>(kb + obase) = ko;
    vt[nl][2 * i] = vv[0];
    vt[nl][2 * i + 1] = vv[1];
  }
  __syncthreads();
  for (int it = 0; it < 32; ++it) {
    int u = it * 256 + t;   // (d 0..63) x (nl 0..127)
    int d = u >> 7, nl = u & 127;
    vT[((size_t)bh * DH + d) * Nn + n0 + nl] = vt[nl][d];
  }
}

// ---------------- flash attention: swapped QK^T, in-register softmax, no LDS ----------------
// Per wave: 32 q-rows. S^T = K·Q^T via mfma_32x32x16 (lane = q-column, 16 k-rows in regs).
// Grid: flat 512 blocks, XCD-owned heads: xcd = bid&7 owns bh in [xcd*4, xcd*4+4)
// -> each XCD's L2 working set = 4 heads x 512 KB = 2 MB (fits 4 MB), K/V re-reads hit L2.
__global__ __launch_bounds__(256, 2) void attn_kernel(const bf16* __restrict__ qb,
                                                      const bf16* __restrict__ kb,
                                                      const bf16* __restrict__ vT,
                                                      bf16* __restrict__ outb) {
  const int lane = threadIdx.x & 63;
  const int wave = threadIdx.x >> 6;
  const int bid = blockIdx.x;
  const int xcd = bid & 7;         // dispatch round-robins consecutive ids across XCDs
  const int idx = bid >> 3;        // 0..63 within this XCD
  const int bh = xcd * 4 + (idx >> 4);
  const int qt = idx & 15;
  const int b = bh >> 4, h = bh & 15;
  const int lo = lane & 31;
  const int hi = lane >> 5;
  const int q0 = qt * 128 + wave * 32;
  const bf16* qptr = qb + (size_t)bh * Nn * DH;
  const bf16* kptr = kb + (size_t)bh * Nn * DH;
  const bf16* vptr = vT + (size_t)bh * DH * Nn;

  constexpr float SCL = 0.125f * 1.44269504088896340736f;  // dh^-0.5 * log2(e)

  // Q as B-operand: B[t=dh][c=q], c=lo, t = d*16 + hi*8 + j
  bf16x8 qf[4];
#pragma unroll
  for (int d = 0; d < 4; ++d)
    qf[d] = *reinterpret_cast<const bf16x8*>(qptr + (size_t)(q0 + lo) * DH + d * 16 + hi * 8);

  f32x16 o0 = {}, o1 = {};
  float mrun = -3e38f, lrun = 0.f;

  auto loadK = [&](int key0, bf16x8* kf) {
#pragma unroll
    for (int d = 0; d < 4; ++d)
      kf[d] = *reinterpret_cast<const bf16x8*>(kptr + (size_t)(key0 + lo) * DH + d * 16 + hi * 8);
  };
  auto loadV = [&](int key0, bf16x8* vf) {
#pragma unroll
    for (int dt = 0; dt < 2; ++dt)
#pragma unroll
      for (int kbi = 0; kbi < 2; ++kbi)
        vf[dt * 2 + kbi] = *reinterpret_cast<const bf16x8*>(
            vptr + (size_t)(dt * 32 + lo) * Nn + key0 + kbi * 16 + hi * 8);
  };

  auto cvtpk = [](float a, float b) {
    unsigned w;
    asm("v_cvt_pk_bf16_f32 %0, %1, %2" : "=v"(w) : "v"(a), "v"(b));
    return w;
  };

  auto tilestep = [&](const bf16x8* kf, const bf16x8* vf) {
    f32x16 s = {};
#pragma unroll
    for (int d = 0; d < 4; ++d)
      s = __builtin_amdgcn_mfma_f32_32x32x16_bf16(kf[d], qf[d], s, 0, 0, 0);

    // row-max over 32 k for this lane's q-column
    float tm = s[0];
#pragma unroll
    for (int r = 1; r < 16; ++r) tm = fmaxf(tm, s[r]);
    tm = fmaxf(tm, __shfl_xor(tm, 32));
    float tms = tm * SCL;

    // T13 defer-max: rescale only when max grows past threshold (wave-uniform branch)
    if (__any(tms > mrun + 8.0f)) {
      float mn = fmaxf(mrun, tms);
      float corr = __builtin_amdgcn_exp2f(mrun - mn);
      mrun = mn;
      lrun *= corr;
#pragma unroll
      for (int r = 0; r < 16; ++r) { o0[r] *= corr; o1[r] *= corr; }
    }

    float e[16];
    float ts = 0.f;
#pragma unroll
    for (int r = 0; r < 16; ++r) {
      e[r] = __builtin_amdgcn_exp2f(fmaf(s[r], SCL, -mrun));
      ts += e[r];
    }
    ts += __shfl_xor(ts, 32);
    lrun += ts;

    // P^T (f32 regs) -> bf16 B-fragments for PV, in-register (T12, shfl variant).
    // Acc reg r holds k = (r&3) + 8*(r>>2) + 4*hi.
    // B-frag for k-block kbi needs k = kbi*16 + hi*8 + j.
    // Each lane SENDS the half its partner needs: hi=0 sends Y (e[4..7]), hi=1 sends X (e[0..3]).
    union { unsigned w[4]; bf16x8 v8; } pb[2];
#pragma unroll
    for (int kbi = 0; kbi < 2; ++kbi) {
      unsigned X0 = cvtpk(e[kbi * 8 + 0], e[kbi * 8 + 1]);
      unsigned X1 = cvtpk(e[kbi * 8 + 2], e[kbi * 8 + 3]);
      unsigned Y0 = cvtpk(e[kbi * 8 + 4], e[kbi * 8 + 5]);
      unsigned Y1 = cvtpk(e[kbi * 8 + 6], e[kbi * 8 + 7]);
      unsigned S0 = hi ? X0 : Y0;        // what the partner needs
      unsigned S1 = hi ? X1 : Y1;
      unsigned T0 = __shfl_xor(S0, 32);  // what we need from partner
      unsigned T1 = __shfl_xor(S1, 32);
      pb[kbi].w[0] = hi ? T0 : X0;
      pb[kbi].w[1] = hi ? T1 : X1;
      pb[kbi].w[2] = hi ? Y0 : T0;
      pb[kbi].w[3] = hi ? Y1 : T1;
    }

    // PV: O^T[dh,q] += V^T[dh,k] P^T[k,q]
    o0 = __builtin_amdgcn_mfma_f32_32x32x16_bf16(vf[0], pb[0].v8, o0, 0, 0, 0);
    o0 = __builtin_amdgcn_mfma_f32_32x32x16_bf16(vf[1], pb[1].v8, o0, 0, 0, 0);
    o1 = __builtin_amdgcn_mfma_f32_32x32x16_bf16(vf[2], pb[0].v8, o1, 0, 0, 0);
    o1 = __builtin_amdgcn_mfma_f32_32x32x16_bf16(vf[3], pb[1].v8, o1, 0, 0, 0);
  };

  // double-buffered K/V fragments, prefetch one tile ahead
  bf16x8 kA[4], vA[4], kB[4], vB[4];
  loadK(0, kA);
  loadV(0, vA);
  for (int t = 0; t < 64; t += 2) {
    int n1 = (t + 1) * 32;
    loadK(n1, kB);
    loadV(n1, vB);
    tilestep(kA, vA);
    int n2 = (t + 2 < 64) ? (t + 2) * 32 : 0;  // last prefetch harmless
    loadK(n2, kA);
    loadV(n2, vA);
    tilestep(kB, vB);
  }

  // epilogue: O^T/l -> outb[B,N,H*DH]; lane owns q-row q0+lo
  float invl = 1.0f / lrun;
#pragma unroll
  for (int dt = 0; dt < 2; ++dt) {
#pragma unroll
    for (int g = 0; g < 4; ++g) {
      bf16x4 ov;
#pragma unroll
      for (int j = 0; j < 4; ++j) {
        float val = (dt ? o1[g * 4 + j] : o0[g * 4 + j]) * invl;
        ov[j] = (bf16)val;
      }
      int dh = dt * 32 + g * 8 + hi * 4;
      *reinterpret_cast<bf16x4*>(outb + (size_t)(b * Nn + q0 + lo) * HID + h * DH + dh) = ov;
    }
  }
}

// ---------------- launch ----------------
extern "C" void kernel_launch(void* const* d_in, const int* in_sizes, int n_in,
                              void* d_out, int out_size, void* d_ws, size_t ws_size,
                              hipStream_t stream) {
  const float* x = (const float*)d_in[0];
  const float* rope = (const float*)d_in[1];
  const float* Wqkv = (const float*)d_in[2];
  const float* Wout = (const float*)d_in[3];
  float* out = (float*)d_out;

  char* w = (char*)d_ws;
  size_t off = 0;
  auto alloc = [&](size_t bytes) -> void* {
    void* p = w + off;
    off += (bytes + 255) & ~(size_t)255;
    return p;
  };
  bf16* xb    = (bf16*)alloc((size_t)MTOK * HID * 2);
  bf16* wqkvb = (bf16*)alloc((size_t)E3 * HID * 2);
  bf16* woutb = (bf16*)alloc((size_t)HID * HID * 2);
  bf16* qkvb  = (bf16*)alloc((size_t)MTOK * E3 * 2);
  bf16* qbuf  = (bf16*)alloc((size_t)Bb * Hh * Nn * DH * 2);
  bf16* kbuf  = (bf16*)alloc((size_t)Bb * Hh * Nn * DH * 2);
  bf16* vTbuf = (bf16*)alloc((size_t)Bb * Hh * Nn * DH * 2);
  bf16* attno = (bf16*)alloc((size_t)MTOK * HID * 2);

  cast_kernel<<<(MTOK * HID / 4) / 256, 256, 0, stream>>>(x, xb, MTOK * HID / 4);
  cast_kernel<<<(E3 * HID / 4) / 256, 256, 0, stream>>>(Wqkv, wqkvb, E3 * HID / 4);
  cast_kernel<<<(HID * HID / 4) / 256, 256, 0, stream>>>(Wout, woutb, HID * HID / 4);

  gemm_bt<true><<<dim3(MTOK / 128, E3 / 128), 256, 0, stream>>>(xb, wqkvb, qkvb, MTOK, E3, HID);

  rope_pack<<<dim3(Nn / 128, Bb * Hh), 256, 0, stream>>>(qkvb, rope, qbuf, kbuf, vTbuf);

  attn_kernel<<<dim3(512), 256, 0, stream>>>(qbuf, kbuf, vTbuf, attno);

  gemm_bt<false><<<dim3(MTOK / 128, HID / 128), 256, 0, stream>>>(attno, woutb, out, MTOK, HID, HID);
}

// Round 7
// 205.106 us; speedup vs baseline: 1.1676x; 1.0013x over previous
//
#include <hip/hip_runtime.h>
#include <stdint.h>
#include <stddef.h>

typedef __bf16 bf16;
typedef __bf16 bf16x2 __attribute__((ext_vector_type(2)));
typedef __bf16 bf16x4 __attribute__((ext_vector_type(4)));
typedef __bf16 bf16x8 __attribute__((ext_vector_type(8)));
typedef float f32x2 __attribute__((ext_vector_type(2)));
typedef float f32x4 __attribute__((ext_vector_type(4)));
typedef float f32x16 __attribute__((ext_vector_type(16)));

constexpr int Bb = 2, Nn = 2048, HID = 1024, Hh = 16, DH = 64;
constexpr int MTOK = Bb * Nn;   // 4096
constexpr int E3 = 3 * Hh * DH; // 3072

// ---------------- cast f32 -> bf16, vectorized ----------------
__global__ void cast_kernel(const float* __restrict__ in, bf16* __restrict__ out, int n4) {
  int i = blockIdx.x * blockDim.x + threadIdx.x;
  if (i >= n4) return;
  f32x4 v = reinterpret_cast<const f32x4*>(in)[i];
  bf16x4 o;
#pragma unroll
  for (int j = 0; j < 4; ++j) o[j] = (bf16)v[j];
  reinterpret_cast<bf16x4*>(out)[i] = o;
}

// ---------------- BT GEMM: C[M,N] = A[M,K] * Bt[N,K]^T ----------------
template <bool OUT_BF16>
__global__ __launch_bounds__(256) void gemm_bt(const bf16* __restrict__ A,
                                               const bf16* __restrict__ Bt,
                                               void* __restrict__ Cp,
                                               int M, int N, int K) {
  __shared__ __align__(16) bf16 As[128 * 32];
  __shared__ __align__(16) bf16 Bs[128 * 32];
  const int tid = threadIdx.x;
  const int lane = tid & 63;
  const int wave = tid >> 6;
  const int wr = wave >> 1, wc = wave & 1;
  const int bm = blockIdx.x, bn = blockIdx.y;
  const int frow = lane & 15;
  const int fk = (lane >> 4) * 8;
  const int c0 = wave * 128 + lane;

  f32x4 acc[4][4] = {};

  for (int k0 = 0; k0 < K; k0 += 32) {
#pragma unroll
    for (int i = 0; i < 2; ++i) {
      int c = c0 + i * 64;               // chunk 0..511, 16B each
      int row = c >> 2;
      int col = (c & 3) * 8;
      const bf16* ga = A + (size_t)(bm * 128 + row) * K + k0 + col;
      const bf16* gb = Bt + (size_t)(bn * 128 + row) * K + k0 + col;
      __builtin_amdgcn_global_load_lds((const __attribute__((address_space(1))) void*)ga,
                                       (__attribute__((address_space(3))) void*)(As + c * 8),
                                       16, 0, 0);
      __builtin_amdgcn_global_load_lds((const __attribute__((address_space(1))) void*)gb,
                                       (__attribute__((address_space(3))) void*)(Bs + c * 8),
                                       16, 0, 0);
    }
    __syncthreads();
    bf16x8 af[4], bfr[4];
#pragma unroll
    for (int m = 0; m < 4; ++m)
      af[m] = *reinterpret_cast<const bf16x8*>(As + (wr * 64 + m * 16 + frow) * 32 + fk);
#pragma unroll
    for (int n = 0; n < 4; ++n)
      bfr[n] = *reinterpret_cast<const bf16x8*>(Bs + (wc * 64 + n * 16 + frow) * 32 + fk);
#pragma unroll
    for (int m = 0; m < 4; ++m)
#pragma unroll
      for (int n = 0; n < 4; ++n)
        acc[m][n] = __builtin_amdgcn_mfma_f32_16x16x32_bf16(af[m], bfr[n], acc[m][n], 0, 0, 0);
    __syncthreads();
  }

  const int r0 = bm * 128 + wr * 64;
  const int cc0 = bn * 128 + wc * 64;
#pragma unroll
  for (int m = 0; m < 4; ++m)
#pragma unroll
    for (int n = 0; n < 4; ++n)
#pragma unroll
      for (int r = 0; r < 4; ++r) {
        int row = r0 + m * 16 + (lane >> 4) * 4 + r;
        int col = cc0 + n * 16 + frow;
        if (OUT_BF16)
          ((bf16*)Cp)[(size_t)row * N + col] = (bf16)acc[m][n][r];
        else
          ((float*)Cp)[(size_t)row * N + col] = acc[m][n][r];
      }
}

// ---------------- RoPE + repack: qkv[B,N,3,H,DH] -> q,k [B,H,N,DH], vT [B,H,DH,N] ----------------
__global__ __launch_bounds__(256) void rope_pack(const bf16* __restrict__ qkvb,
                                                 const float* __restrict__ rope,
                                                 bf16* __restrict__ qb,
                                                 bf16* __restrict__ kb,
                                                 bf16* __restrict__ vT) {
  __shared__ bf16 vt[128][66];  // padded: conflict-free transpose
  const int bh = blockIdx.y;
  const int b = bh >> 4;
  const int h = bh & 15;
  const int n0 = blockIdx.x * 128;
  const int t = threadIdx.x;

  for (int it = 0; it < 16; ++it) {
    int p = it * 256 + t;   // (row 0..127) x (pair 0..31)
    int nl = p >> 5, i = p & 31;
    int n = n0 + nl;
    size_t rowbase = (size_t)(b * Nn + n);
    const bf16* src = qkvb + rowbase * E3 + h * DH + 2 * i;
    f32x2 cs = *reinterpret_cast<const f32x2*>(rope + rowbase * DH + 2 * i);
    float c = cs[0], sn = cs[1];
    bf16x2 qv = *reinterpret_cast<const bf16x2*>(src);
    bf16x2 kv = *reinterpret_cast<const bf16x2*>(src + HID);
    bf16x2 vv = *reinterpret_cast<const bf16x2*>(src + 2 * HID);
    float q0 = (float)qv[0], q1 = (float)qv[1];
    float k0 = (float)kv[0], k1 = (float)kv[1];
    bf16x2 qo, ko;
    qo[0] = (bf16)(q0 * c - q1 * sn);
    qo[1] = (bf16)(q1 * c + q0 * sn);
    ko[0] = (bf16)(k0 * c - k1 * sn);
    ko[1] = (bf16)(k1 * c + k0 * sn);
    size_t obase = ((size_t)bh * Nn + n) * DH + 2 * i;
    *reinterpret_cast<bf16x2*>(qb + obase) = qo;
    *reinterpret_cast<bf16x2*>(kb + obase) = ko;
    vt[nl][2 * i] = vv[0];
    vt[nl][2 * i + 1] = vv[1];
  }
  __syncthreads();
  for (int it = 0; it < 32; ++it) {
    int u = it * 256 + t;   // (d 0..63) x (nl 0..127)
    int d = u >> 7, nl = u & 127;
    vT[((size_t)bh * DH + d) * Nn + n0 + nl] = vt[nl][d];
  }
}

// ---------------- flash attention: swapped QK^T, in-register softmax, no LDS ----------------
// Per wave: 32 q-rows, KVBLK=64 (two 32x32x16 S-chains for ILP).
// XCD-owned heads (bid&7 -> 4 heads each) keep K/V in the XCD's private L2.
// sched_barrier(0) pins next-tile K prefetch before the current tilestep (real in-flight loads).
// Cross-half exchange uses __shfl_xor(.,32) (proven); permlane32_swap deferred to a later A/B.
__global__ __launch_bounds__(256, 2) void attn_kernel(const bf16* __restrict__ qb,
                                                      const bf16* __restrict__ kb,
                                                      const bf16* __restrict__ vT,
                                                      bf16* __restrict__ outb) {
  const int lane = threadIdx.x & 63;
  const int wave = threadIdx.x >> 6;
  const int bid = blockIdx.x;
  const int xcd = bid & 7;         // dispatch round-robins consecutive ids across XCDs
  const int idx = bid >> 3;        // 0..63 within this XCD
  const int bh = xcd * 4 + (idx >> 4);
  const int qt = idx & 15;
  const int b = bh >> 4, h = bh & 15;
  const int lo = lane & 31;
  const int hi = lane >> 5;
  const int q0 = qt * 128 + wave * 32;
  const bf16* qptr = qb + (size_t)bh * Nn * DH;
  const bf16* kptr = kb + (size_t)bh * Nn * DH;
  const bf16* vptr = vT + (size_t)bh * DH * Nn;

  constexpr float SCL = 0.125f * 1.44269504088896340736f;  // dh^-0.5 * log2(e)

  // Q as B-operand: B[t=dh][c=q], c=lo, t = d*16 + hi*8 + j
  bf16x8 qf[4];
#pragma unroll
  for (int d = 0; d < 4; ++d)
    qf[d] = *reinterpret_cast<const bf16x8*>(qptr + (size_t)(q0 + lo) * DH + d * 16 + hi * 8);

  f32x16 o0 = {}, o1 = {};
  float mrun = -3e38f, lrun = 0.f;

  auto cvtpk = [](float a, float b) {
    unsigned w;
    asm("v_cvt_pk_bf16_f32 %0, %1, %2" : "=v"(w) : "v"(a), "v"(b));
    return w;
  };

  auto loadK64 = [&](int key0, bf16x8* kf) {
#pragma unroll
    for (int half = 0; half < 2; ++half)
#pragma unroll
      for (int d = 0; d < 4; ++d)
        kf[half * 4 + d] = *reinterpret_cast<const bf16x8*>(
            kptr + (size_t)(key0 + half * 32 + lo) * DH + d * 16 + hi * 8);
  };

  auto tilestep64 = [&](int key0, const bf16x8* kf) {
    // V loads issue first; consumed only at PV -> latency hidden under QK^T + softmax
    bf16x8 vf[8];
#pragma unroll
    for (int dt = 0; dt < 2; ++dt)
#pragma unroll
      for (int kbi = 0; kbi < 4; ++kbi)
        vf[dt * 4 + kbi] = *reinterpret_cast<const bf16x8*>(
            vptr + (size_t)(dt * 32 + lo) * Nn + key0 + kbi * 16 + hi * 8);

    // two independent S accumulator chains (keys 0-31 / 32-63 of the tile)
    f32x16 s0 = {}, s1 = {};
#pragma unroll
    for (int d = 0; d < 4; ++d) {
      s0 = __builtin_amdgcn_mfma_f32_32x32x16_bf16(kf[d], qf[d], s0, 0, 0, 0);
      s1 = __builtin_amdgcn_mfma_f32_32x32x16_bf16(kf[4 + d], qf[d], s1, 0, 0, 0);
    }

    // tree max over 32 values (depth ~5)
    float t16[16];
#pragma unroll
    for (int r = 0; r < 16; ++r) t16[r] = fmaxf(s0[r], s1[r]);
#pragma unroll
    for (int r = 0; r < 8; ++r) t16[r] = fmaxf(t16[r], t16[r + 8]);
#pragma unroll
    for (int r = 0; r < 4; ++r) t16[r] = fmaxf(t16[r], t16[r + 4]);
    float tmv = fmaxf(fmaxf(t16[0], t16[2]), fmaxf(t16[1], t16[3]));
    float tm = fmaxf(tmv, __shfl_xor(tmv, 32));
    float tms = tm * SCL;

    // T13 defer-max: rescale only when max grows past threshold (wave-uniform branch)
    if (__any(tms > mrun + 8.0f)) {
      float mn = fmaxf(mrun, tms);
      float corr = __builtin_amdgcn_exp2f(mrun - mn);
      mrun = mn;
      lrun *= corr;
#pragma unroll
      for (int r = 0; r < 16; ++r) { o0[r] *= corr; o1[r] *= corr; }
    }

    float e[32];
#pragma unroll
    for (int r = 0; r < 16; ++r) e[r] = __builtin_amdgcn_exp2f(fmaf(s0[r], SCL, -mrun));
#pragma unroll
    for (int r = 0; r < 16; ++r) e[16 + r] = __builtin_amdgcn_exp2f(fmaf(s1[r], SCL, -mrun));

    // tree sum
    float u[16];
#pragma unroll
    for (int r = 0; r < 16; ++r) u[r] = e[r] + e[16 + r];
#pragma unroll
    for (int r = 0; r < 8; ++r) u[r] += u[r + 8];
#pragma unroll
    for (int r = 0; r < 4; ++r) u[r] += u[r + 4];
    float tsv = (u[0] + u[2]) + (u[1] + u[3]);
    lrun += tsv + __shfl_xor(tsv, 32);

    // P^T -> bf16 B-fragments (T12). Acc reg r of block bl holds k = bl*32 + (r&3)+8*(r>>2)+4*hi.
    // B-frag kbi needs k = kbi*16 + hi*8 + j. Lane sends the half its partner needs:
    // hi=0 sends Y (its e[eo+4..7]), hi=1 sends X (its e[eo+0..3]).
    union { unsigned w[4]; bf16x8 v8; } pb[4];
#pragma unroll
    for (int kbi = 0; kbi < 4; ++kbi) {
      const int eo = (kbi >> 1) * 16 + (kbi & 1) * 8;
      unsigned X0 = cvtpk(e[eo + 0], e[eo + 1]);
      unsigned X1 = cvtpk(e[eo + 2], e[eo + 3]);
      unsigned Y0 = cvtpk(e[eo + 4], e[eo + 5]);
      unsigned Y1 = cvtpk(e[eo + 6], e[eo + 7]);
      unsigned S0 = hi ? X0 : Y0;            // what the partner needs
      unsigned S1 = hi ? X1 : Y1;
      unsigned T0 = __shfl_xor(S0, 32);      // what we need from partner
      unsigned T1 = __shfl_xor(S1, 32);
      pb[kbi].w[0] = hi ? T0 : X0;
      pb[kbi].w[1] = hi ? T1 : X1;
      pb[kbi].w[2] = hi ? Y0 : T0;
      pb[kbi].w[3] = hi ? Y1 : T1;
    }

    // PV: O^T[dh,q] += V^T[dh,k] P^T[k,q]  (two independent acc chains)
#pragma unroll
    for (int kbi = 0; kbi < 4; ++kbi) {
      o0 = __builtin_amdgcn_mfma_f32_32x32x16_bf16(vf[kbi], pb[kbi].v8, o0, 0, 0, 0);
      o1 = __builtin_amdgcn_mfma_f32_32x32x16_bf16(vf[4 + kbi], pb[kbi].v8, o1, 0, 0, 0);
    }
  };

  // K double-buffered across tiles; sched_barrier pins prefetch issue before the tilestep
  bf16x8 kA[8], kB[8];
  loadK64(0, kA);
  for (int t = 0; t < 32; t += 2) {
    loadK64((t + 1) * 64, kB);
    __builtin_amdgcn_sched_barrier(0);
    tilestep64(t * 64, kA);
    int n2 = (t + 2 < 32) ? (t + 2) * 64 : 0;  // last prefetch harmless
    loadK64(n2, kA);
    __builtin_amdgcn_sched_barrier(0);
    tilestep64((t + 1) * 64, kB);
  }

  // epilogue: O^T/l -> outb[B,N,H*DH]; lane owns q-row q0+lo
  float invl = 1.0f / lrun;
#pragma unroll
  for (int dt = 0; dt < 2; ++dt) {
#pragma unroll
    for (int g = 0; g < 4; ++g) {
      bf16x4 ov;
#pragma unroll
      for (int j = 0; j < 4; ++j) {
        float val = (dt ? o1[g * 4 + j] : o0[g * 4 + j]) * invl;
        ov[j] = (bf16)val;
      }
      int dh = dt * 32 + g * 8 + hi * 4;
      *reinterpret_cast<bf16x4*>(outb + (size_t)(b * Nn + q0 + lo) * HID + h * DH + dh) = ov;
    }
  }
}

// ---------------- launch ----------------
extern "C" void kernel_launch(void* const* d_in, const int* in_sizes, int n_in,
                              void* d_out, int out_size, void* d_ws, size_t ws_size,
                              hipStream_t stream) {
  const float* x = (const float*)d_in[0];
  const float* rope = (const float*)d_in[1];
  const float* Wqkv = (const float*)d_in[2];
  const float* Wout = (const float*)d_in[3];
  float* out = (float*)d_out;

  char* w = (char*)d_ws;
  size_t off = 0;
  auto alloc = [&](size_t bytes) -> void* {
    void* p = w + off;
    off += (bytes + 255) & ~(size_t)255;
    return p;
  };
  bf16* xb    = (bf16*)alloc((size_t)MTOK * HID * 2);
  bf16* wqkvb = (bf16*)alloc((size_t)E3 * HID * 2);
  bf16* woutb = (bf16*)alloc((size_t)HID * HID * 2);
  bf16* qkvb  = (bf16*)alloc((size_t)MTOK * E3 * 2);
  bf16* qbuf  = (bf16*)alloc((size_t)Bb * Hh * Nn * DH * 2);
  bf16* kbuf  = (bf16*)alloc((size_t)Bb * Hh * Nn * DH * 2);
  bf16* vTbuf = (bf16*)alloc((size_t)Bb * Hh * Nn * DH * 2);
  bf16* attno = (bf16*)alloc((size_t)MTOK * HID * 2);

  cast_kernel<<<(MTOK * HID / 4) / 256, 256, 0, stream>>>(x, xb, MTOK * HID / 4);
  cast_kernel<<<(E3 * HID / 4) / 256, 256, 0, stream>>>(Wqkv, wqkvb, E3 * HID / 4);
  cast_kernel<<<(HID * HID / 4) / 256, 256, 0, stream>>>(Wout, woutb, HID * HID / 4);

  gemm_bt<true><<<dim3(MTOK / 128, E3 / 128), 256, 0, stream>>>(xb, wqkvb, qkvb, MTOK, E3, HID);

  rope_pack<<<dim3(Nn / 128, Bb * Hh), 256, 0, stream>>>(qkvb, rope, qbuf, kbuf, vTbuf);

  attn_kernel<<<dim3(512), 256, 0, stream>>>(qbuf, kbuf, vTbuf, attno);

  gemm_bt<false><<<dim3(MTOK / 128, HID / 128), 256, 0, stream>>>(attno, woutb, out, MTOK, HID, HID);
}

// Round 8
// 143.809 us; speedup vs baseline: 1.6653x; 1.4262x over previous
//
#include <hip/hip_runtime.h>
#include <stdint.h>
#include <stddef.h>

typedef __bf16 bf16;
typedef __bf16 bf16x2 __attribute__((ext_vector_type(2)));
typedef __bf16 bf16x4 __attribute__((ext_vector_type(4)));
typedef __bf16 bf16x8 __attribute__((ext_vector_type(8)));
typedef float f32x2 __attribute__((ext_vector_type(2)));
typedef float f32x4 __attribute__((ext_vector_type(4)));
typedef float f32x16 __attribute__((ext_vector_type(16)));

constexpr int Bb = 2, Nn = 2048, HID = 1024, Hh = 16, DH = 64;
constexpr int MTOK = Bb * Nn;   // 4096
constexpr int E3 = 3 * Hh * DH; // 3072

// ---------------- cast f32 -> bf16, vectorized ----------------
__global__ void cast_kernel(const float* __restrict__ in, bf16* __restrict__ out, int n4) {
  int i = blockIdx.x * blockDim.x + threadIdx.x;
  if (i >= n4) return;
  f32x4 v = reinterpret_cast<const f32x4*>(in)[i];
  bf16x4 o;
#pragma unroll
  for (int j = 0; j < 4; ++j) o[j] = (bf16)v[j];
  reinterpret_cast<bf16x4*>(out)[i] = o;
}

// ---------------- BT GEMM: C[M,N] = A[M,K] * Bt[N,K]^T ----------------
template <bool OUT_BF16>
__global__ __launch_bounds__(256) void gemm_bt(const bf16* __restrict__ A,
                                               const bf16* __restrict__ Bt,
                                               void* __restrict__ Cp,
                                               int M, int N, int K) {
  __shared__ __align__(16) bf16 As[128 * 32];
  __shared__ __align__(16) bf16 Bs[128 * 32];
  const int tid = threadIdx.x;
  const int lane = tid & 63;
  const int wave = tid >> 6;
  const int wr = wave >> 1, wc = wave & 1;
  const int bm = blockIdx.x, bn = blockIdx.y;
  const int frow = lane & 15;
  const int fk = (lane >> 4) * 8;
  const int c0 = wave * 128 + lane;

  f32x4 acc[4][4] = {};

  for (int k0 = 0; k0 < K; k0 += 32) {
#pragma unroll
    for (int i = 0; i < 2; ++i) {
      int c = c0 + i * 64;               // chunk 0..511, 16B each
      int row = c >> 2;
      int col = (c & 3) * 8;
      const bf16* ga = A + (size_t)(bm * 128 + row) * K + k0 + col;
      const bf16* gb = Bt + (size_t)(bn * 128 + row) * K + k0 + col;
      __builtin_amdgcn_global_load_lds((const __attribute__((address_space(1))) void*)ga,
                                       (__attribute__((address_space(3))) void*)(As + c * 8),
                                       16, 0, 0);
      __builtin_amdgcn_global_load_lds((const __attribute__((address_space(1))) void*)gb,
                                       (__attribute__((address_space(3))) void*)(Bs + c * 8),
                                       16, 0, 0);
    }
    __syncthreads();
    bf16x8 af[4], bfr[4];
#pragma unroll
    for (int m = 0; m < 4; ++m)
      af[m] = *reinterpret_cast<const bf16x8*>(As + (wr * 64 + m * 16 + frow) * 32 + fk);
#pragma unroll
    for (int n = 0; n < 4; ++n)
      bfr[n] = *reinterpret_cast<const bf16x8*>(Bs + (wc * 64 + n * 16 + frow) * 32 + fk);
#pragma unroll
    for (int m = 0; m < 4; ++m)
#pragma unroll
      for (int n = 0; n < 4; ++n)
        acc[m][n] = __builtin_amdgcn_mfma_f32_16x16x32_bf16(af[m], bfr[n], acc[m][n], 0, 0, 0);
    __syncthreads();
  }

  const int r0 = bm * 128 + wr * 64;
  const int cc0 = bn * 128 + wc * 64;
#pragma unroll
  for (int m = 0; m < 4; ++m)
#pragma unroll
    for (int n = 0; n < 4; ++n)
#pragma unroll
      for (int r = 0; r < 4; ++r) {
        int row = r0 + m * 16 + (lane >> 4) * 4 + r;
        int col = cc0 + n * 16 + frow;
        if (OUT_BF16)
          ((bf16*)Cp)[(size_t)row * N + col] = (bf16)acc[m][n][r];
        else
          ((float*)Cp)[(size_t)row * N + col] = acc[m][n][r];
      }
}

// ---------------- RoPE + fragment-pack ----------------
// Emits Q,K,V in MFMA-fragment-packed order so attention loads are base+lane*16B (coalesced).
//  q/k (B-operand, 32-row blocks): qpk[((bh*64+blk)*4+d)*64+lane] = Q[blk*32+(lane&31)][d*16+(lane>>5)*8 ..+8]
//  v   (A-operand, 64-key tiles):  vpk[((bh*32+kt)*8+dt*4+kbi)*64+lane]
//                                   = V[kt*64+kbi*16+(lane>>5)*8+j][dt*32+(lane&31)]  (j=0..7)
__global__ __launch_bounds__(256) void rope_pack(const bf16* __restrict__ qkvb,
                                                 const float* __restrict__ rope,
                                                 bf16* __restrict__ qpk,
                                                 bf16* __restrict__ kpk,
                                                 bf16* __restrict__ vpk) {
  __shared__ bf16 qs[128][66];
  __shared__ bf16 ks[128][66];
  __shared__ bf16 vs[128][66];
  const int bh = blockIdx.y;
  const int b = bh >> 4;
  const int h = bh & 15;
  const int n0 = blockIdx.x * 128;
  const int t = threadIdx.x;

  // phase A: rope + stage to LDS
  for (int it = 0; it < 16; ++it) {
    int p = it * 256 + t;   // (row 0..127) x (pair 0..31)
    int nl = p >> 5, i = p & 31;
    int n = n0 + nl;
    size_t rowbase = (size_t)(b * Nn + n);
    const bf16* src = qkvb + rowbase * E3 + h * DH + 2 * i;
    f32x2 cs = *reinterpret_cast<const f32x2*>(rope + rowbase * DH + 2 * i);
    float c = cs[0], sn = cs[1];
    bf16x2 qv = *reinterpret_cast<const bf16x2*>(src);
    bf16x2 kv = *reinterpret_cast<const bf16x2*>(src + HID);
    bf16x2 vv = *reinterpret_cast<const bf16x2*>(src + 2 * HID);
    float q0 = (float)qv[0], q1 = (float)qv[1];
    float k0 = (float)kv[0], k1 = (float)kv[1];
    qs[nl][2 * i]     = (bf16)(q0 * c - q1 * sn);
    qs[nl][2 * i + 1] = (bf16)(q1 * c + q0 * sn);
    ks[nl][2 * i]     = (bf16)(k0 * c - k1 * sn);
    ks[nl][2 * i + 1] = (bf16)(k1 * c + k0 * sn);
    vs[nl][2 * i]     = vv[0];
    vs[nl][2 * i + 1] = vv[1];
  }
  __syncthreads();

  // phase B1: q/k fragment-pack (coalesced 16B stores)
  const int lane2 = t & 63;
  const int dd = t >> 6;              // 0..3
  const int lo2 = lane2 & 31, hi2 = lane2 >> 5;
#pragma unroll
  for (int kbq = 0; kbq < 4; ++kbq) {
    int row = kbq * 32 + lo2;
    int col = dd * 16 + hi2 * 8;
    bf16x8 q8 = *reinterpret_cast<const bf16x8*>(&qs[row][col]);
    bf16x8 k8 = *reinterpret_cast<const bf16x8*>(&ks[row][col]);
    size_t base = ((((size_t)bh * 64 + (n0 >> 5) + kbq) * 4 + dd) * 64 + lane2) * 8;
    *reinterpret_cast<bf16x8*>(qpk + base) = q8;
    *reinterpret_cast<bf16x8*>(kpk + base) = k8;
  }

  // phase B2: v fragment-pack (transpose gather from LDS, coalesced 16B stores)
#pragma unroll
  for (int wi = 0; wi < 4; ++wi) {
    int id = wi * 256 + t;
    int lane3 = id & 63;
    int sub = id >> 6;                // 0..15
    int kt = sub >> 3, dt = (sub >> 2) & 1, kbi = sub & 3;
    int lo3 = lane3 & 31, hi3 = lane3 >> 5;
    bf16x8 v8;
#pragma unroll
    for (int j = 0; j < 8; ++j)
      v8[j] = vs[kt * 64 + kbi * 16 + hi3 * 8 + j][dt * 32 + lo3];
    size_t vbase = ((((size_t)bh * 32 + (n0 >> 6) + kt) * 8 + dt * 4 + kbi) * 64 + lane3) * 8;
    *reinterpret_cast<bf16x8*>(vpk + vbase) = v8;
  }
}

// ---------------- flash attention: swapped QK^T, in-register softmax, packed coalesced loads ----------------
// Per wave: 32 q-rows, KVBLK=64. All operand loads are base+lane*16B (one 1KB burst per inst).
// XCD-owned heads (bid&7 -> 4 heads each) keep K/V in the XCD's private L2.
__global__ __launch_bounds__(256, 2) void attn_kernel(const bf16* __restrict__ qpk,
                                                      const bf16* __restrict__ kpk,
                                                      const bf16* __restrict__ vpk,
                                                      bf16* __restrict__ outb) {
  const int lane = threadIdx.x & 63;
  const int wave = threadIdx.x >> 6;
  const int bid = blockIdx.x;
  const int xcd = bid & 7;
  const int idx = bid >> 3;
  const int bh = xcd * 4 + (idx >> 4);
  const int qt = idx & 15;
  const int b = bh >> 4, h = bh & 15;
  const int lo = lane & 31;
  const int hi = lane >> 5;
  const int q0 = qt * 128 + wave * 32;

  constexpr float SCL = 0.125f * 1.44269504088896340736f;  // dh^-0.5 * log2(e)

  // Q fragments (packed, coalesced)
  bf16x8 qf[4];
#pragma unroll
  for (int d = 0; d < 4; ++d)
    qf[d] = *reinterpret_cast<const bf16x8*>(
        qpk + ((((size_t)bh * 64 + qt * 4 + wave) * 4 + d) * 64 + lane) * 8);

  f32x16 o0 = {}, o1 = {};
  float mrun = -3e38f, lrun = 0.f;

  auto cvtpk = [](float a, float b) {
    unsigned w;
    asm("v_cvt_pk_bf16_f32 %0, %1, %2" : "=v"(w) : "v"(a), "v"(b));
    return w;
  };

  auto loadK64 = [&](int key0, bf16x8* kf) {
    size_t base = (((size_t)bh * 64 + (key0 >> 5)) * 4 * 64 + lane) * 8;
#pragma unroll
    for (int half = 0; half < 2; ++half)
#pragma unroll
      for (int d = 0; d < 4; ++d)
        kf[half * 4 + d] = *reinterpret_cast<const bf16x8*>(
            kpk + base + (half * 4 + d) * 512);
  };

  auto tilestep64 = [&](int key0, const bf16x8* kf) {
    // V loads issue first (coalesced); consumed at PV -> latency hidden under QK^T + softmax
    bf16x8 vf[8];
    size_t vbase = (((size_t)bh * 32 + (key0 >> 6)) * 8 * 64 + lane) * 8;
#pragma unroll
    for (int sub = 0; sub < 8; ++sub)
      vf[sub] = *reinterpret_cast<const bf16x8*>(vpk + vbase + sub * 512);

    // two independent S accumulator chains (keys 0-31 / 32-63 of the tile)
    f32x16 s0 = {}, s1 = {};
#pragma unroll
    for (int d = 0; d < 4; ++d) {
      s0 = __builtin_amdgcn_mfma_f32_32x32x16_bf16(kf[d], qf[d], s0, 0, 0, 0);
      s1 = __builtin_amdgcn_mfma_f32_32x32x16_bf16(kf[4 + d], qf[d], s1, 0, 0, 0);
    }

    // tree max over 32 values
    float t16[16];
#pragma unroll
    for (int r = 0; r < 16; ++r) t16[r] = fmaxf(s0[r], s1[r]);
#pragma unroll
    for (int r = 0; r < 8; ++r) t16[r] = fmaxf(t16[r], t16[r + 8]);
#pragma unroll
    for (int r = 0; r < 4; ++r) t16[r] = fmaxf(t16[r], t16[r + 4]);
    float tmv = fmaxf(fmaxf(t16[0], t16[2]), fmaxf(t16[1], t16[3]));
    float tm = fmaxf(tmv, __shfl_xor(tmv, 32));
    float tms = tm * SCL;

    // T13 defer-max
    if (__any(tms > mrun + 8.0f)) {
      float mn = fmaxf(mrun, tms);
      float corr = __builtin_amdgcn_exp2f(mrun - mn);
      mrun = mn;
      lrun *= corr;
#pragma unroll
      for (int r = 0; r < 16; ++r) { o0[r] *= corr; o1[r] *= corr; }
    }

    float e[32];
#pragma unroll
    for (int r = 0; r < 16; ++r) e[r] = __builtin_amdgcn_exp2f(fmaf(s0[r], SCL, -mrun));
#pragma unroll
    for (int r = 0; r < 16; ++r) e[16 + r] = __builtin_amdgcn_exp2f(fmaf(s1[r], SCL, -mrun));

    // tree sum
    float u[16];
#pragma unroll
    for (int r = 0; r < 16; ++r) u[r] = e[r] + e[16 + r];
#pragma unroll
    for (int r = 0; r < 8; ++r) u[r] += u[r + 8];
#pragma unroll
    for (int r = 0; r < 4; ++r) u[r] += u[r + 4];
    float tsv = (u[0] + u[2]) + (u[1] + u[3]);
    lrun += tsv + __shfl_xor(tsv, 32);

    // P^T -> bf16 B-fragments (T12, shfl variant; layout as derived in R3/R7)
    union { unsigned w[4]; bf16x8 v8; } pb[4];
#pragma unroll
    for (int kbi = 0; kbi < 4; ++kbi) {
      const int eo = (kbi >> 1) * 16 + (kbi & 1) * 8;
      unsigned X0 = cvtpk(e[eo + 0], e[eo + 1]);
      unsigned X1 = cvtpk(e[eo + 2], e[eo + 3]);
      unsigned Y0 = cvtpk(e[eo + 4], e[eo + 5]);
      unsigned Y1 = cvtpk(e[eo + 6], e[eo + 7]);
      unsigned S0 = hi ? X0 : Y0;
      unsigned S1 = hi ? X1 : Y1;
      unsigned T0 = __shfl_xor(S0, 32);
      unsigned T1 = __shfl_xor(S1, 32);
      pb[kbi].w[0] = hi ? T0 : X0;
      pb[kbi].w[1] = hi ? T1 : X1;
      pb[kbi].w[2] = hi ? Y0 : T0;
      pb[kbi].w[3] = hi ? Y1 : T1;
    }

    // PV: O^T[dh,q] += V^T[dh,k] P^T[k,q]
#pragma unroll
    for (int kbi = 0; kbi < 4; ++kbi) {
      o0 = __builtin_amdgcn_mfma_f32_32x32x16_bf16(vf[kbi], pb[kbi].v8, o0, 0, 0, 0);
      o1 = __builtin_amdgcn_mfma_f32_32x32x16_bf16(vf[4 + kbi], pb[kbi].v8, o1, 0, 0, 0);
    }
  };

  // K double-buffered across tiles; sched_barrier pins prefetch issue before the tilestep
  bf16x8 kA[8], kB[8];
  loadK64(0, kA);
  for (int t = 0; t < 32; t += 2) {
    loadK64((t + 1) * 64, kB);
    __builtin_amdgcn_sched_barrier(0);
    tilestep64(t * 64, kA);
    int n2 = (t + 2 < 32) ? (t + 2) * 64 : 0;  // last prefetch harmless
    loadK64(n2, kA);
    __builtin_amdgcn_sched_barrier(0);
    tilestep64((t + 1) * 64, kB);
  }

  // epilogue: O^T/l -> outb[B,N,H*DH]; lane owns q-row q0+lo
  float invl = 1.0f / lrun;
#pragma unroll
  for (int dt = 0; dt < 2; ++dt) {
#pragma unroll
    for (int g = 0; g < 4; ++g) {
      bf16x4 ov;
#pragma unroll
      for (int j = 0; j < 4; ++j) {
        float val = (dt ? o1[g * 4 + j] : o0[g * 4 + j]) * invl;
        ov[j] = (bf16)val;
      }
      int dh = dt * 32 + g * 8 + hi * 4;
      *reinterpret_cast<bf16x4*>(outb + (size_t)(b * Nn + q0 + lo) * HID + h * DH + dh) = ov;
    }
  }
}

// ---------------- launch ----------------
extern "C" void kernel_launch(void* const* d_in, const int* in_sizes, int n_in,
                              void* d_out, int out_size, void* d_ws, size_t ws_size,
                              hipStream_t stream) {
  const float* x = (const float*)d_in[0];
  const float* rope = (const float*)d_in[1];
  const float* Wqkv = (const float*)d_in[2];
  const float* Wout = (const float*)d_in[3];
  float* out = (float*)d_out;

  char* w = (char*)d_ws;
  size_t off = 0;
  auto alloc = [&](size_t bytes) -> void* {
    void* p = w + off;
    off += (bytes + 255) & ~(size_t)255;
    return p;
  };
  bf16* xb    = (bf16*)alloc((size_t)MTOK * HID * 2);
  bf16* wqkvb = (bf16*)alloc((size_t)E3 * HID * 2);
  bf16* woutb = (bf16*)alloc((size_t)HID * HID * 2);
  bf16* qkvb  = (bf16*)alloc((size_t)MTOK * E3 * 2);
  bf16* qpk   = (bf16*)alloc((size_t)Bb * Hh * Nn * DH * 2);
  bf16* kpk   = (bf16*)alloc((size_t)Bb * Hh * Nn * DH * 2);
  bf16* vpk   = (bf16*)alloc((size_t)Bb * Hh * Nn * DH * 2);
  bf16* attno = (bf16*)alloc((size_t)MTOK * HID * 2);

  cast_kernel<<<(MTOK * HID / 4) / 256, 256, 0, stream>>>(x, xb, MTOK * HID / 4);
  cast_kernel<<<(E3 * HID / 4) / 256, 256, 0, stream>>>(Wqkv, wqkvb, E3 * HID / 4);
  cast_kernel<<<(HID * HID / 4) / 256, 256, 0, stream>>>(Wout, woutb, HID * HID / 4);

  gemm_bt<true><<<dim3(MTOK / 128, E3 / 128), 256, 0, stream>>>(xb, wqkvb, qkvb, MTOK, E3, HID);

  rope_pack<<<dim3(Nn / 128, Bb * Hh), 256, 0, stream>>>(qkvb, rope, qpk, kpk, vpk);

  attn_kernel<<<dim3(512), 256, 0, stream>>>(qpk, kpk, vpk, attno);

  gemm_bt<false><<<dim3(MTOK / 128, HID / 128), 256, 0, stream>>>(attno, woutb, out, MTOK, HID, HID);
}